// Round 1
// baseline (103.392 us; speedup 1.0000x reference)
//
#include <hip/hip_runtime.h>
#include <math.h>

// Problem constants (from reference setup_inputs)
#define N_   8
#define C_   384
#define H_   112
#define W_   112
#define HW_  (H_*W_)            // 12544
#define CHW_ ((long long)C_*HW_) // 4816896
#define HID_ 24
#define NPLANES (N_*C_)         // 3072
#define VEC4_PER_PLANE (HW_/4)  // 3136
#define GN_EPS 1e-5

// permuted source plane for output (j, c):
// c < 128: src sample = c>>4, src channel = j*16 + (c&15)
// c >= 128: identity
__device__ __forceinline__ int src_plane(int j, int c) {
    if (c < 128) {
        int i = c >> 4, d = c & 15;
        return i * C_ + j * 16 + d;
    }
    return j * C_ + c;
}

// ---------------- Kernel 1: per-plane sum / sumsq ----------------
__global__ __launch_bounds__(256) void k_stats(const float* __restrict__ x,
                                               float* __restrict__ S,
                                               float* __restrict__ Q) {
    int p = blockIdx.x;  // plane index 0..3071
    const float4* x4 = (const float4*)x + (size_t)p * VEC4_PER_PLANE;
    float s = 0.f, q = 0.f;
    for (int i = threadIdx.x; i < VEC4_PER_PLANE; i += 256) {
        float4 v = x4[i];
        s += v.x + v.y + v.z + v.w;
        q += v.x*v.x + v.y*v.y + v.z*v.z + v.w*v.w;
    }
    // wave (64-lane) reduce
    for (int off = 32; off; off >>= 1) {
        s += __shfl_down(s, off);
        q += __shfl_down(q, off);
    }
    __shared__ float ss[4], sq[4];
    int lane = threadIdx.x & 63, wid = threadIdx.x >> 6;
    if (lane == 0) { ss[wid] = s; sq[wid] = q; }
    __syncthreads();
    if (threadIdx.x == 0) {
        S[p] = ss[0] + ss[1] + ss[2] + ss[3];
        Q[p] = sq[0] + sq[1] + sq[2] + sq[3];
    }
}

// ---------------- Kernel 2: stats + SE + coefficients ----------------
__global__ __launch_bounds__(512) void k_se(const float* __restrict__ S,
                                            const float* __restrict__ Q,
                                            const float* __restrict__ gw,
                                            const float* __restrict__ gb,
                                            const float* __restrict__ w1,
                                            const float* __restrict__ w2,
                                            float* __restrict__ A,
                                            float* __restrict__ B,
                                            float* __restrict__ Cst) {
    __shared__ float sS[NPLANES];
    __shared__ float sg[NPLANES];
    __shared__ float sh1[N_*HID_];
    __shared__ float smu[N_], sinv[N_];
    int tid = threadIdx.x;
    for (int i = tid; i < NPLANES; i += 512) sS[i] = S[i];
    __syncthreads();

    // wave j (8 waves of 64 lanes) computes mu/var for sample j over the
    // permuted channel set (which is a bijection, so just enumerate it)
    {
        int j = tid >> 6, lane = tid & 63;
        double ds = 0.0, dq = 0.0;
        for (int t = lane; t < C_; t += 64) {
            int idx;
            if (t < 128) { int i = t >> 4, d = t & 15; idx = i * C_ + j * 16 + d; }
            else idx = j * C_ + t;
            ds += (double)sS[idx];
            dq += (double)Q[idx];
        }
        for (int off = 32; off; off >>= 1) {
            ds += __shfl_down(ds, off);
            dq += __shfl_down(dq, off);
        }
        if (lane == 0) {
            double mu = ds / (double)CHW_;
            double var = dq / (double)CHW_ - mu * mu;
            smu[j]  = (float)mu;
            sinv[j] = (float)(1.0 / sqrt(var + GN_EPS));
        }
    }
    __syncthreads();

    // g[j][c] = mean_hw(z) computed from plane sums only
    const float invHW = 1.0f / (float)HW_;
    for (int i = tid; i < NPLANES; i += 512) {
        int j = i / C_, c = i % C_;
        int src = src_plane(j, c);
        sg[i] = sS[i] * invHW + (sS[src] * invHW - smu[j]) * sinv[j] * gw[c] + gb[c];
    }
    __syncthreads();

    // h1 = relu(g @ w1)  [8 x 24]
    if (tid < N_ * HID_) {
        int j = tid / HID_, k = tid % HID_;
        float acc = 0.f;
        for (int c = 0; c < C_; ++c) acc += sg[j * C_ + c] * w1[c * HID_ + k];
        sh1[tid] = fmaxf(acc, 0.f);
    }
    __syncthreads();

    // h2 = h1 @ w2; s = sigmoid(h2); emit fused coefficients
    for (int i = tid; i < NPLANES; i += 512) {
        int j = i / C_, c = i % C_;
        float h2 = 0.f;
        for (int k = 0; k < HID_; ++k) h2 += sh1[j * HID_ + k] * w2[k * C_ + c];
        float s = 1.f / (1.f + expf(-h2));
        float ivg = sinv[j] * gw[c];
        A[i]   = s;
        B[i]   = s * ivg;
        Cst[i] = s * (gb[c] - smu[j] * ivg);
    }
}

// ---------------- Kernel 3: out = A*x_self + B*x_perm + C ----------------
__global__ __launch_bounds__(256) void k_out(const float* __restrict__ x,
                                             const float* __restrict__ A,
                                             const float* __restrict__ B,
                                             const float* __restrict__ Cst,
                                             float* __restrict__ out) {
    int p = blockIdx.x;
    int j = p / C_, c = p % C_;
    int src = src_plane(j, c);
    float a = A[p], b = B[p], cst = Cst[p];
    const float4* xa = (const float4*)x + (size_t)p   * VEC4_PER_PLANE;
    const float4* xb = (const float4*)x + (size_t)src * VEC4_PER_PLANE;
    float4* o4 = (float4*)out + (size_t)p * VEC4_PER_PLANE;
    for (int i = threadIdx.x; i < VEC4_PER_PLANE; i += 256) {
        float4 va = xa[i], vb = xb[i];
        float4 r;
        r.x = a * va.x + b * vb.x + cst;
        r.y = a * va.y + b * vb.y + cst;
        r.z = a * va.z + b * vb.z + cst;
        r.w = a * va.w + b * vb.w + cst;
        o4[i] = r;
    }
}

extern "C" void kernel_launch(void* const* d_in, const int* in_sizes, int n_in,
                              void* d_out, int out_size, void* d_ws, size_t ws_size,
                              hipStream_t stream) {
    const float* x  = (const float*)d_in[0];
    const float* gw = (const float*)d_in[1];
    const float* gb = (const float*)d_in[2];
    const float* w1 = (const float*)d_in[3];
    const float* w2 = (const float*)d_in[4];
    float* out = (float*)d_out;

    float* ws = (float*)d_ws;
    float* S   = ws;                // 3072
    float* Q   = ws + NPLANES;      // 3072
    float* A   = ws + 2 * NPLANES;  // 3072
    float* B   = ws + 3 * NPLANES;  // 3072
    float* Cst = ws + 4 * NPLANES;  // 3072

    k_stats<<<NPLANES, 256, 0, stream>>>(x, S, Q);
    k_se<<<1, 512, 0, stream>>>(S, Q, gw, gb, w1, w2, A, B, Cst);
    k_out<<<NPLANES, 256, 0, stream>>>(x, A, B, Cst, out);
}

// Round 3
// 83.271 us; speedup vs baseline: 1.2416x; 1.2416x over previous
//
#include <hip/hip_runtime.h>
#include <math.h>

// Problem constants (from reference setup_inputs)
#define N_   8
#define C_   384
#define H_   112
#define W_   112
#define HW_  (H_*W_)             // 12544
#define CHW_ 4816896.0           // C*H*W per sample
#define HID_ 24
#define NPLANES (N_*C_)          // 3072
#define V4P (HW_/4)              // 3136 float4 per plane
#define GN_EPS 1e-5

typedef float f32x4 __attribute__((ext_vector_type(4)));

// permuted source plane for output (j, c):
// c < 128: src sample = c>>4, src channel = j*16 + (c&15); else identity
__device__ __forceinline__ int src_plane(int j, int c) {
    if (c < 128) { int i = c >> 4, d = c & 15; return i * C_ + j * 16 + d; }
    return j * C_ + c;
}

// ---------------- Kernel 1: per-plane sum / sumsq ----------------
__global__ __launch_bounds__(256) void k_stats(const float* __restrict__ x,
                                               float* __restrict__ S,
                                               float* __restrict__ Q) {
    int p = blockIdx.x;  // plane 0..3071
    const f32x4* x4 = (const f32x4*)x + (size_t)p * V4P;
    float s = 0.f, q = 0.f;
    for (int i = threadIdx.x; i < V4P; i += 256) {
        f32x4 v = x4[i];
        s += v.x + v.y + v.z + v.w;
        q += v.x*v.x + v.y*v.y + v.z*v.z + v.w*v.w;
    }
    for (int off = 32; off; off >>= 1) {
        s += __shfl_down(s, off);
        q += __shfl_down(q, off);
    }
    __shared__ float ss[4], sq[4];
    int lane = threadIdx.x & 63, wid = threadIdx.x >> 6;
    if (lane == 0) { ss[wid] = s; sq[wid] = q; }
    __syncthreads();
    if (threadIdx.x == 0) {
        S[p] = ss[0] + ss[1] + ss[2] + ss[3];
        Q[p] = sq[0] + sq[1] + sq[2] + sq[3];
    }
}

// ---------------- Kernel 2: one block per sample ----------------
__global__ __launch_bounds__(256) void k_sample(const float* __restrict__ S,
                                                const float* __restrict__ Q,
                                                const float* __restrict__ gw,
                                                const float* __restrict__ gb,
                                                const float* __restrict__ w1,
                                                const float* __restrict__ w2,
                                                float* __restrict__ A,
                                                float* __restrict__ B,
                                                float* __restrict__ Cst) {
    const int j = blockIdx.x;        // sample 0..7
    const int tid = threadIdx.x;
    const int lane = tid & 63, wid = tid >> 6;
    __shared__ double dred[2][4];
    __shared__ float sg[C_];
    __shared__ float hpart[8][HID_];
    __shared__ float h1s[HID_];
    __shared__ float smu, sinv;

    // mu, var over the permuted channel set (a bijection of plane indices)
    double ds = 0.0, dq = 0.0;
    for (int t = tid; t < C_; t += 256) {
        int idx = src_plane(j, t);
        ds += (double)S[idx];
        dq += (double)Q[idx];
    }
    for (int off = 32; off; off >>= 1) {
        ds += __shfl_down(ds, off);
        dq += __shfl_down(dq, off);
    }
    if (lane == 0) { dred[0][wid] = ds; dred[1][wid] = dq; }
    __syncthreads();
    if (tid == 0) {
        double tds = dred[0][0] + dred[0][1] + dred[0][2] + dred[0][3];
        double tdq = dred[1][0] + dred[1][1] + dred[1][2] + dred[1][3];
        double mu = tds / CHW_;
        double var = tdq / CHW_ - mu * mu;
        smu  = (float)mu;
        sinv = (float)(1.0 / sqrt(var + GN_EPS));
    }
    __syncthreads();
    const float fmu = smu, finv = sinv;

    // g[j][c] from plane sums only
    const float invHW = 1.0f / (float)HW_;
    for (int c = tid; c < C_; c += 256) {
        int self = j * C_ + c, src = src_plane(j, c);
        sg[c] = S[self] * invHW + (S[src] * invHW - fmu) * finv * gw[c] + gb[c];
    }
    __syncthreads();

    // h1 = relu(g @ w1): 192 threads, 8 c-groups x 24 k
    if (tid < 192) {
        int k = tid % HID_, grp = tid / HID_;
        float acc = 0.f;
        int c0 = grp * 48;
        for (int c = c0; c < c0 + 48; ++c) acc += sg[c] * w1[c * HID_ + k];
        hpart[grp][k] = acc;
    }
    __syncthreads();
    if (tid < HID_) {
        float a = 0.f;
        for (int g2 = 0; g2 < 8; ++g2) a += hpart[g2][tid];
        h1s[tid] = fmaxf(a, 0.f);
    }
    __syncthreads();

    // per-plane coefficients; w2[k*C+c] is coalesced across c
    for (int c = tid; c < C_; c += 256) {
        float h2 = 0.f;
        for (int k = 0; k < HID_; ++k) h2 += h1s[k] * w2[k * C_ + c];
        float s = 1.f / (1.f + expf(-h2));
        float ivg = finv * gw[c];
        int p = j * C_ + c;
        A[p]   = s;
        B[p]   = s * ivg;
        Cst[p] = s * (gb[c] - fmu * ivg);
    }
}

// ---------------- Kernel 3: out = A*x_self + B*x_perm + C (nt stores) ----------------
__global__ __launch_bounds__(256) void k_out(const float* __restrict__ x,
                                             const float* __restrict__ A,
                                             const float* __restrict__ B,
                                             const float* __restrict__ Cst,
                                             float* __restrict__ out) {
    int p = blockIdx.x;
    int j = p / C_, c = p - j * C_;
    float a = A[p], b = B[p], cst = Cst[p];
    const f32x4* xa = (const f32x4*)x + (size_t)p * V4P;
    f32x4* o4 = (f32x4*)out + (size_t)p * V4P;
    if (c >= 128) {
        // identity plane: single load, combined scale
        float ab = a + b;
        for (int i = threadIdx.x; i < V4P; i += 256) {
            f32x4 v = xa[i];
            f32x4 r;
            r.x = ab * v.x + cst;
            r.y = ab * v.y + cst;
            r.z = ab * v.z + cst;
            r.w = ab * v.w + cst;
            __builtin_nontemporal_store(r, o4 + i);
        }
    } else {
        int src = src_plane(j, c);
        const f32x4* xb = (const f32x4*)x + (size_t)src * V4P;
        for (int i = threadIdx.x; i < V4P; i += 256) {
            f32x4 va = xa[i], vb = xb[i];
            f32x4 r;
            r.x = a * va.x + b * vb.x + cst;
            r.y = a * va.y + b * vb.y + cst;
            r.z = a * va.z + b * vb.z + cst;
            r.w = a * va.w + b * vb.w + cst;
            __builtin_nontemporal_store(r, o4 + i);
        }
    }
}

extern "C" void kernel_launch(void* const* d_in, const int* in_sizes, int n_in,
                              void* d_out, int out_size, void* d_ws, size_t ws_size,
                              hipStream_t stream) {
    const float* x  = (const float*)d_in[0];
    const float* gw = (const float*)d_in[1];
    const float* gb = (const float*)d_in[2];
    const float* w1 = (const float*)d_in[3];
    const float* w2 = (const float*)d_in[4];
    float* out = (float*)d_out;

    float* ws = (float*)d_ws;
    float* S   = ws;                // 3072
    float* Q   = ws + NPLANES;      // 3072
    float* A   = ws + 2 * NPLANES;  // 3072
    float* B   = ws + 3 * NPLANES;  // 3072
    float* Cst = ws + 4 * NPLANES;  // 3072

    k_stats<<<NPLANES, 256, 0, stream>>>(x, S, Q);
    k_sample<<<N_, 256, 0, stream>>>(S, Q, gw, gb, w1, w2, A, B, Cst);
    k_out<<<NPLANES, 256, 0, stream>>>(x, A, B, Cst, out);
}

// Round 4
// 80.041 us; speedup vs baseline: 1.2917x; 1.0403x over previous
//
#include <hip/hip_runtime.h>
#include <math.h>

// Problem constants (from reference setup_inputs)
#define N_   8
#define C_   384
#define H_   112
#define W_   112
#define HW_  (H_*W_)             // 12544
#define CHW_ 4816896.0           // C*H*W per sample
#define HID_ 24
#define NPLANES (N_*C_)          // 3072
#define V4P (HW_/4)              // 3136 float4 per plane
#define GN_EPS 1e-5

typedef float f32x4 __attribute__((ext_vector_type(4)));

// permuted source plane for output (j, c):
// c < 128: src sample = c>>4, src channel = j*16 + (c&15); else identity
__device__ __forceinline__ int src_plane(int j, int c) {
    if (c < 128) { int i = c >> 4, d = c & 15; return i * C_ + j * 16 + d; }
    return j * C_ + c;
}

// ---------------- Kernel 1: per-plane sum / sumsq ----------------
__global__ __launch_bounds__(256) void k_stats(const float* __restrict__ x,
                                               float* __restrict__ S,
                                               float* __restrict__ Q) {
    int p = blockIdx.x;  // plane 0..3071
    const f32x4* x4 = (const f32x4*)x + (size_t)p * V4P;
    float s = 0.f, q = 0.f;
    for (int i = threadIdx.x; i < V4P; i += 256) {
        f32x4 v = x4[i];
        s += v.x + v.y + v.z + v.w;
        q += v.x*v.x + v.y*v.y + v.z*v.z + v.w*v.w;
    }
    for (int off = 32; off; off >>= 1) {
        s += __shfl_down(s, off);
        q += __shfl_down(q, off);
    }
    __shared__ float ss[4], sq[4];
    int lane = threadIdx.x & 63, wid = threadIdx.x >> 6;
    if (lane == 0) { ss[wid] = s; sq[wid] = q; }
    __syncthreads();
    if (threadIdx.x == 0) {
        S[p] = ss[0] + ss[1] + ss[2] + ss[3];
        Q[p] = sq[0] + sq[1] + sq[2] + sq[3];
    }
}

// ---------------- Kernel 2: one block per sample ----------------
__global__ __launch_bounds__(256) void k_sample(const float* __restrict__ S,
                                                const float* __restrict__ Q,
                                                const float* __restrict__ gw,
                                                const float* __restrict__ gb,
                                                const float* __restrict__ w1,
                                                const float* __restrict__ w2,
                                                float* __restrict__ A,
                                                float* __restrict__ B,
                                                float* __restrict__ Cst) {
    const int j = blockIdx.x;        // sample 0..7
    const int tid = threadIdx.x;
    const int lane = tid & 63, wid = tid >> 6;
    __shared__ double dred[2][4];
    __shared__ float sg[C_];
    __shared__ float hpart[8][HID_];
    __shared__ float h1s[HID_];
    __shared__ float smu, sinv;

    // mu, var over the permuted channel set (a bijection of plane indices)
    double ds = 0.0, dq = 0.0;
    for (int t = tid; t < C_; t += 256) {
        int idx = src_plane(j, t);
        ds += (double)S[idx];
        dq += (double)Q[idx];
    }
    for (int off = 32; off; off >>= 1) {
        ds += __shfl_down(ds, off);
        dq += __shfl_down(dq, off);
    }
    if (lane == 0) { dred[0][wid] = ds; dred[1][wid] = dq; }
    __syncthreads();
    if (tid == 0) {
        double tds = dred[0][0] + dred[0][1] + dred[0][2] + dred[0][3];
        double tdq = dred[1][0] + dred[1][1] + dred[1][2] + dred[1][3];
        double mu = tds / CHW_;
        double var = tdq / CHW_ - mu * mu;
        smu  = (float)mu;
        sinv = (float)(1.0 / sqrt(var + GN_EPS));
    }
    __syncthreads();
    const float fmu = smu, finv = sinv;

    // g[j][c] from plane sums only
    const float invHW = 1.0f / (float)HW_;
    for (int c = tid; c < C_; c += 256) {
        int self = j * C_ + c, src = src_plane(j, c);
        sg[c] = S[self] * invHW + (S[src] * invHW - fmu) * finv * gw[c] + gb[c];
    }
    __syncthreads();

    // h1 = relu(g @ w1): 192 threads, 8 c-groups x 24 k
    if (tid < 192) {
        int k = tid % HID_, grp = tid / HID_;
        float acc = 0.f;
        int c0 = grp * 48;
        for (int c = c0; c < c0 + 48; ++c) acc += sg[c] * w1[c * HID_ + k];
        hpart[grp][k] = acc;
    }
    __syncthreads();
    if (tid < HID_) {
        float a = 0.f;
        for (int g2 = 0; g2 < 8; ++g2) a += hpart[g2][tid];
        h1s[tid] = fmaxf(a, 0.f);
    }
    __syncthreads();

    // per-plane coefficients; w2[k*C+c] is coalesced across c
    for (int c = tid; c < C_; c += 256) {
        float h2 = 0.f;
        for (int k = 0; k < HID_; ++k) h2 += h1s[k] * w2[k * C_ + c];
        float s = 1.f / (1.f + expf(-h2));
        float ivg = finv * gw[c];
        int p = j * C_ + c;
        A[p]   = s;
        B[p]   = s * ivg;
        Cst[p] = s * (gb[c] - fmu * ivg);
    }
}

// ---------------- Kernel 3: paired output ----------------
// Blocks 0..447: pair-blocks. Pair (i<j, d): plane P=(j, i*16+d) and
// plane Q=(i, j*16+d) are each other's permutation source. Load both x
// planes once, emit both outputs -> zero duplicate global reads.
// Blocks 448..2623: single planes where src==self (identity c>=128, and
// the 128 self-pair planes (j, j*16+d)): out = (a+b)*x + c.
#define NPAIR 448
#define NSELF 128
__global__ __launch_bounds__(256) void k_out(const float* __restrict__ x,
                                             const float* __restrict__ A,
                                             const float* __restrict__ B,
                                             const float* __restrict__ Cst,
                                             float* __restrict__ out) {
    int bidx = blockIdx.x;
    if (bidx < NPAIR) {
        int combo = bidx >> 4, d = bidx & 15;
        // unrank combo -> (i, j) with i < j among 8 samples
        int i = 0, j = 1, c2 = combo;
        for (i = 0; i < 8; ++i) {
            int cnt = 7 - i;
            if (c2 < cnt) { j = i + 1 + c2; break; }
            c2 -= cnt;
        }
        int P  = j * C_ + i * 16 + d;   // plane (j, c=i*16+d)
        int Qp = i * C_ + j * 16 + d;   // plane (i, c=j*16+d)
        float aP = A[P],  bP = B[P],  cP = Cst[P];
        float aQ = A[Qp], bQ = B[Qp], cQ = Cst[Qp];
        const f32x4* xP = (const f32x4*)x + (size_t)P  * V4P;
        const f32x4* xQ = (const f32x4*)x + (size_t)Qp * V4P;
        f32x4* oP = (f32x4*)out + (size_t)P  * V4P;
        f32x4* oQ = (f32x4*)out + (size_t)Qp * V4P;
        for (int t = threadIdx.x; t < V4P; t += 256) {
            f32x4 vp = xP[t], vq = xQ[t];
            f32x4 rp = vp * aP + vq * bP + cP;
            f32x4 rq = vq * aQ + vp * bQ + cQ;
            __builtin_nontemporal_store(rp, oP + t);
            __builtin_nontemporal_store(rq, oQ + t);
        }
    } else {
        int t = bidx - NPAIR;
        int p;
        if (t < NSELF) {
            int j = t >> 4, d = t & 15;
            p = j * C_ + j * 16 + d;          // self-pair plane
        } else {
            int t2 = t - NSELF;
            int j = t2 >> 8, c = 128 + (t2 & 255);  // identity planes c>=128
            p = j * C_ + c;
        }
        float ab = A[p] + B[p], cst = Cst[p];
        const f32x4* xa = (const f32x4*)x + (size_t)p * V4P;
        f32x4* o4 = (f32x4*)out + (size_t)p * V4P;
        for (int i = threadIdx.x; i < V4P; i += 256) {
            f32x4 r = xa[i] * ab + cst;
            __builtin_nontemporal_store(r, o4 + i);
        }
    }
}

extern "C" void kernel_launch(void* const* d_in, const int* in_sizes, int n_in,
                              void* d_out, int out_size, void* d_ws, size_t ws_size,
                              hipStream_t stream) {
    const float* x  = (const float*)d_in[0];
    const float* gw = (const float*)d_in[1];
    const float* gb = (const float*)d_in[2];
    const float* w1 = (const float*)d_in[3];
    const float* w2 = (const float*)d_in[4];
    float* out = (float*)d_out;

    float* ws = (float*)d_ws;
    float* S   = ws;                // 3072
    float* Q   = ws + NPLANES;      // 3072
    float* A   = ws + 2 * NPLANES;  // 3072
    float* B   = ws + 3 * NPLANES;  // 3072
    float* Cst = ws + 4 * NPLANES;  // 3072

    k_stats<<<NPLANES, 256, 0, stream>>>(x, S, Q);
    k_sample<<<N_, 256, 0, stream>>>(S, Q, gw, gb, w1, w2, A, B, Cst);
    k_out<<<NPAIR + NSELF + 2048, 256, 0, stream>>>(x, A, B, Cst, out);
}